// Round 1
// baseline (1123.165 us; speedup 1.0000x reference)
//
#include <hip/hip_runtime.h>
#include <math.h>

#define NB_IN   128   // 2*B_IN beta samples
#define NBINS   39    // alpha freqs m = -19..19
#define NLM     400   // B_OUT^2
#define NZI     256   // BATCH*F_IN
#define NZO     512   // BATCH*F_OUT
#define NLMN    10660 // sum_{l<20} (2l+1)^2
#define TWOB    40    // 2*B_INV
#define PI_D    3.14159265358979323846
#define SCALING 0.008164965809277261  // 1/sqrt(24*16*20^4/64^2) = 1/sqrt(15000)

__host__ __device__ __forceinline__ int off_l(int l){ return l*(2*l-1)*(2*l+1)/3; }

__device__ __forceinline__ int lidx(int lm){
  int l = (int)sqrtf((float)lm);
  while ((l+1)*(l+1) <= lm) ++l;
  while (l*l > lm) --l;
  return l;
}

// Wigner little-d via Jacobi sum, double precision, lg = log-factorial table
__device__ double wigner_d(int l, int m, int n, double beta, const double* lg){
  double cb = cos(0.5*beta), sb = sin(0.5*beta);
  double lcb = log(cb), lsb = log(sb);
  double pref = 0.5*(lg[l+m]+lg[l-m]+lg[l+n]+lg[l-n]);
  int s0 = 0 > (n-m) ? 0 : (n-m);
  int s1 = (l+n) < (l-m) ? (l+n) : (l-m);
  double val = 0.0;
  for (int s = s0; s <= s1; ++s){
    double c = pref - (lg[l+n-s]+lg[s]+lg[m-n+s]+lg[l-m-s]);
    double t = exp(c + (double)(2*l+n-m-2*s)*lcb + (double)(m-n+2*s)*lsb);
    val += ((m-n+s)&1) ? -t : t;
  }
  return val;
}

// ---- constants kernels -------------------------------------------------
__global__ void k_init(double* lg, double* wq){
  int t = threadIdx.x;  // 128
  if (t == 0){
    lg[0] = 0.0; double acc = 0.0;
    for (int k = 1; k <= 40; ++k){ acc += log((double)k); lg[k] = acc; }
  }
  double theta = PI_D*(2*t+1)/256.0;
  double s = 0.0;
  for (int k = 0; k < 64; ++k) s += sin((2*k+1)*theta)/(double)(2*k+1);
  wq[t] = (2.0/64.0)*sin(theta)*s;
}

__global__ void k_tw(float2* tw){
  int tid = blockIdx.x*256 + threadIdx.x;
  if (tid >= NBINS*NB_IN) return;
  int mj = tid / NB_IN, a = tid % NB_IN;
  double ang = -2.0*PI_D*(double)(mj-19)*(double)a/128.0;
  tw[tid] = make_float2((float)cos(ang), (float)sin(ang));
}

__global__ void k_ws2(float* w_s2, const double* lg, const double* wq){
  int tid = blockIdx.x*256 + threadIdx.x;
  if (tid >= NB_IN*NLM) return;
  int b = tid / NLM, lm = tid % NLM;
  int l = lidx(lm); int m = lm - l*l - l;
  double beta = PI_D*(2*b+1)/256.0;
  w_s2[tid] = (float)(wigner_d(l, m, 0, beta, lg) * wq[b]);
}

__global__ void k_dinv(float* dinv, const double* lg){
  int l = blockIdx.y; int W = 2*l+1;
  int j = blockIdx.x*256 + threadIdx.x;
  if (j >= TWOB*39*39) return;
  int b = j / (39*39); int r = j % (39*39);
  int mi = r / 39, ni = r % 39;
  if (mi >= W || ni >= W) return;
  double beta = PI_D*(2*b+1)/80.0;
  double d = (double)W * wigner_d(l, mi-l, ni-l, beta, lg);
  dinv[TWOB*off_l(l) + b*W*W + mi*W + ni] = (float)d;
}

__global__ void k_Fc(float2* Fc, const double* lg){
  int tid = blockIdx.x*256 + threadIdx.x;
  if (tid >= 24*NLM) return;
  int p = tid / NLM, lm = tid % NLM;
  int l = lidx(lm); int m = lm - l*l - l;
  double beta = PI_D*(double)(p/8 + 1)/24.0;
  double alpha = (double)(p%8)*(PI_D/4.0);
  double d = wigner_d(l, m, 0, beta, lg);
  double a = (double)m*alpha;            // conj(F_k) => e^{+i m alpha}
  Fc[tid] = make_float2((float)(d*cos(a)), (float)(d*sin(a)));
}

__global__ void k_yc(const float* ker, const float2* Fc, float2* yc){
  int tid = blockIdx.x*256 + threadIdx.x;
  if (tid >= NLM*NZO) return;
  int lm = tid / 512, io = tid % 512;
  float2 acc = make_float2(0.f, 0.f);
  for (int p = 0; p < 24; ++p){
    float kv = ker[io*24 + p];          // [i][o][p], io = i*32+o
    float2 f = Fc[p*NLM + lm];
    acc.x += kv*f.x; acc.y += kv*f.y;
  }
  acc.x *= (float)SCALING; acc.y *= (float)SCALING;
  yc[(size_t)lm*512 + io] = acc;        // [lm][i*32+o]
}

// ---- main pipeline -----------------------------------------------------
// xf[mj][b][zi] = sum_a x[zi][b][a] * e^{-2pi i (mj-19) a/128}
__global__ __launch_bounds__(256) void k_dft(const float* x, const float2* tw, float2* xf){
  __shared__ float2 twl[NBINS*129];     // padded stride vs 32 banks
  __shared__ float rows[4][128];
  int t = threadIdx.x;
  for (int e = t; e < NBINS*128; e += 256){
    int mj = e >> 7, a = e & 127;
    twl[mj*129 + a] = tw[e];
  }
  int g = t >> 6, lane = t & 63;
  int r = blockIdx.x*4 + g;
  int zi = r & 255, b = r >> 8;
  const float* xr = x + ((size_t)zi*128 + b)*128;
  rows[g][lane]    = xr[lane];
  rows[g][lane+64] = xr[lane+64];
  __syncthreads();
  if (lane < NBINS){
    float2 acc = make_float2(0.f, 0.f);
    const float2* twr = twl + lane*129;
    const float* rw = rows[g];
    for (int a = 0; a < 128; ++a){
      float v = rw[a]; float2 w = twr[a];
      acc.x += v*w.x; acc.y += v*w.y;
    }
    xf[((size_t)lane*128 + b)*256 + zi] = acc;
  }
}

// xl[lm][zi] = sum_b w_s2[b][lm] * xf[bin(lm)][b][zi]
__global__ void k_xl(const float2* xf, const float* w_s2, float2* xl){
  int lm = blockIdx.x; int zi = threadIdx.x;
  int l = lidx(lm); int m = lm - l*l - l;
  int bin = m + 19;
  float2 acc = make_float2(0.f, 0.f);
  for (int b = 0; b < 128; ++b){
    float w = w_s2[b*NLM + lm];
    float2 v = xf[((size_t)bin*128 + b)*256 + zi];
    acc.x += w*v.x; acc.y += w*v.y;
  }
  xl[(size_t)lm*256 + zi] = acc;
}

// zl[zo][r(l,mi,ni)] = sum_i xl[l^2+mi][z*16+i] * yc[l^2+ni][i*32+o]
__global__ void k_zl(const float2* xl, const float2* yc, float2* zl){
  int tid = blockIdx.x*256 + threadIdx.x;
  if (tid >= NZO*NLMN) return;
  int zo = tid / NLMN, r = tid % NLMN;
  int z = zo >> 5, o = zo & 31;
  int l = 0;
  while (r >= off_l(l+1)) ++l;
  int W = 2*l+1;
  int q = r - off_l(l);
  int mi = q / W, ni = q % W;
  const float2* xr = xl + (size_t)(l*l+mi)*256 + z*16;
  const float2* yr = yc + (size_t)(l*l+ni)*512 + o;
  float2 acc = make_float2(0.f, 0.f);
  for (int i = 0; i < 16; ++i){
    float2 a = xr[i], bb = yr[i*32];
    acc.x += a.x*bb.x - a.y*bb.y;
    acc.y += a.x*bb.y + a.y*bb.x;
  }
  zl[tid] = acc;
}

// per (z,o,b): C[m][n] = sum_l dinv*zl ; G = DFT_n ; out = Re DFT_m + bias
__global__ __launch_bounds__(256) void k_syn(const float2* zl, const float* dinv,
                                             const float* bias, float* out){
  __shared__ float2 C[39*39];
  __shared__ float2 G[39*40];
  __shared__ float2 cis[40];
  int blk = blockIdx.x;            // (z*32+o)*40 + b
  int b = blk % 40, zo = blk / 40;
  int o = zo & 31;
  int t = threadIdx.x;
  if (t < 40){
    double ang = 2.0*PI_D*(double)t/40.0;
    cis[t] = make_float2((float)cos(ang), (float)sin(ang));
  }
  __syncthreads();
  const float2* zrow = zl + (size_t)zo*NLMN;
  for (int idx = t; idx < 39*39; idx += 256){
    int mj = idx/39, nj = idx%39;
    int m = mj-19, n = nj-19;
    int am = m<0?-m:m, an = n<0?-n:n;
    int lmax = am>an?am:an;
    float2 acc = make_float2(0.f, 0.f);
    for (int l = lmax; l < 20; ++l){
      int W = 2*l+1;
      int base = off_l(l) + (m+l)*W + (n+l);
      float dv = dinv[TWOB*off_l(l) + b*W*W + (m+l)*W + (n+l)];
      float2 zv = zrow[base];
      acc.x += dv*zv.x; acc.y += dv*zv.y;
    }
    C[idx] = acc;
  }
  __syncthreads();
  for (int idx = t; idx < 39*40; idx += 256){
    int mj = idx/40, g = idx%40;
    float2 acc = make_float2(0.f, 0.f);
    int k = ((-19*g) % 40 + 40) % 40;
    int step = g % 40;
    for (int nj = 0; nj < 39; ++nj){
      float2 c = C[mj*39+nj];
      float2 w = cis[k];
      acc.x += c.x*w.x - c.y*w.y;
      acc.y += c.x*w.y + c.y*w.x;
      k += step; if (k >= 40) k -= 40;
    }
    G[idx] = acc;
  }
  __syncthreads();
  float bv = bias[o];
  float* orow = out + (size_t)blk*1600;
  for (int idx = t; idx < 1600; idx += 256){
    int a = idx/40, g = idx%40;
    float acc = 0.f;
    int k = ((-19*a) % 40 + 40) % 40;
    int step = a % 40;
    for (int mj = 0; mj < 39; ++mj){
      float2 gv = G[mj*40+g];
      float2 w = cis[k];
      acc += gv.x*w.x - gv.y*w.y;
      k += step; if (k >= 40) k -= 40;
    }
    orow[idx] = acc + bv;
  }
}

extern "C" void kernel_launch(void* const* d_in, const int* in_sizes, int n_in,
                              void* d_out, int out_size, void* d_ws, size_t ws_size,
                              hipStream_t stream) {
  const float* x    = (const float*)d_in[0];
  const float* ker  = (const float*)d_in[1];
  const float* bias = (const float*)d_in[2];
  float* out = (float*)d_out;

  char* ws = (char*)d_ws;
  size_t cur = 0;
  auto alloc = [&](size_t bytes)->char*{
    char* p = ws + cur;
    cur += (bytes + 255) & ~(size_t)255;
    return p;
  };
  double* lg   = (double*)alloc(64*8);
  double* wq   = (double*)alloc(128*8);
  float2* tw   = (float2*)alloc((size_t)NBINS*128*8);
  float*  w_s2 = (float*) alloc((size_t)NB_IN*NLM*4);
  float*  dinv = (float*) alloc((size_t)TWOB*NLMN*4);
  float2* Fc   = (float2*)alloc((size_t)24*NLM*8);
  float2* yc   = (float2*)alloc((size_t)NLM*NZO*8);
  float2* xf   = (float2*)alloc((size_t)NBINS*128*256*8);
  float2* xl   = (float2*)alloc((size_t)NLM*256*8);
  float2* zl   = (float2*)alloc((size_t)NZO*NLMN*8);
  (void)ws_size; (void)in_sizes; (void)n_in; (void)out_size;

  k_init<<<1, 128, 0, stream>>>(lg, wq);
  k_tw  <<<(NBINS*128 + 255)/256, 256, 0, stream>>>(tw);
  k_ws2 <<<(NB_IN*NLM)/256, 256, 0, stream>>>(w_s2, lg, wq);
  k_dinv<<<dim3((TWOB*39*39 + 255)/256, 20), 256, 0, stream>>>(dinv, lg);
  k_Fc  <<<(24*NLM + 255)/256, 256, 0, stream>>>(Fc, lg);
  k_yc  <<<(NLM*NZO)/256, 256, 0, stream>>>(ker, Fc, yc);

  k_dft <<<(256*128)/4, 256, 0, stream>>>(x, tw, xf);
  k_xl  <<<NLM, 256, 0, stream>>>(xf, w_s2, xl);
  k_zl  <<<(NZO*NLMN)/256, 256, 0, stream>>>(xl, yc, zl);
  k_syn <<<NZO*TWOB, 256, 0, stream>>>(zl, dinv, bias, out);
}

// Round 2
// 977.146 us; speedup vs baseline: 1.1494x; 1.1494x over previous
//
#include <hip/hip_runtime.h>
#include <math.h>

#define NB_IN   128   // 2*B_IN beta samples
#define NBINS   39    // alpha freqs m = -19..19
#define NLM     400   // B_OUT^2
#define NZO     512   // BATCH*F_OUT
#define NPAIR   780   // 20 (m>=0) * 39 (n)
#define NPACK   5530  // sum over pairs of (20 - max(m,|n|))
#define TWOB    40    // 2*B_INV
#define PI_D    3.14159265358979323846
#define SCALING 0.008164965809277261  // 1/sqrt(15000)

__device__ __forceinline__ int lidx(int lm){
  int l = (int)sqrtf((float)lm);
  while ((l+1)*(l+1) <= lm) ++l;
  while (l*l > lm) --l;
  return l;
}

// Wigner little-d via Jacobi sum, double precision
__device__ double wigner_d(int l, int m, int n, double beta, const double* lg){
  double cb = cos(0.5*beta), sb = sin(0.5*beta);
  double lcb = log(cb), lsb = log(sb);
  double pref = 0.5*(lg[l+m]+lg[l-m]+lg[l+n]+lg[l-n]);
  int s0 = 0 > (n-m) ? 0 : (n-m);
  int s1 = (l+n) < (l-m) ? (l+n) : (l-m);
  double val = 0.0;
  for (int s = s0; s <= s1; ++s){
    double c = pref - (lg[l+n-s]+lg[s]+lg[m-n+s]+lg[l-m-s]);
    double t = exp(c + (double)(2*l+n-m-2*s)*lcb + (double)(m-n+2*s)*lsb);
    val += ((m-n+s)&1) ? -t : t;
  }
  return val;
}

// ---- constants kernels -------------------------------------------------
__global__ void k_init(double* lg, double* wq, int* pair_off, int* ridx){
  int t = threadIdx.x;  // 128
  if (t == 0){
    lg[0] = 0.0; double acc = 0.0;
    for (int k = 1; k <= 40; ++k){ acc += log((double)k); lg[k] = acc; }
  }
  if (t == 1){
    int off = 0;
    for (int p = 0; p < NPAIR; ++p){
      int mj = p/39, n = p%39 - 19;
      int an = n < 0 ? -n : n;
      int lmin = mj > an ? mj : an;
      pair_off[p] = off;
      for (int l = lmin; l < 20; ++l){ ridx[off] = mj | ((n+19)<<8) | (l<<16); ++off; }
    }
    pair_off[NPAIR] = off; // 5530
  }
  double theta = PI_D*(2*t+1)/256.0;
  double s = 0.0;
  for (int k = 0; k < 64; ++k) s += sin((2*k+1)*theta)/(double)(2*k+1);
  wq[t] = (2.0/64.0)*sin(theta)*s;
}

__global__ void k_tw(float2* tw){
  int tid = blockIdx.x*256 + threadIdx.x;
  if (tid >= NBINS*NB_IN) return;
  int mj = tid / NB_IN, a = tid % NB_IN;
  double ang = -2.0*PI_D*(double)(mj-19)*(double)a/128.0;
  tw[tid] = make_float2((float)cos(ang), (float)sin(ang));
}

__global__ void k_wsyn(float2* wsyn){
  // wsyn[0..1559]   : Wn[njs][g] = e^{ i (njs-19) g 2pi/40 }
  // wsyn[1560..2359]: Wm[mj][a]  = e^{ i mj a 2pi/40 }
  for (int idx = threadIdx.x; idx < 1560+800; idx += 256){
    double ang;
    if (idx < 1560){
      int njs = idx/40, g = idx%40;
      ang = 2.0*PI_D*(double)(njs-19)*(double)g/40.0;
    } else {
      int r = idx-1560; int mj = r/40, a = r%40;
      ang = 2.0*PI_D*(double)mj*(double)a/40.0;
    }
    wsyn[idx] = make_float2((float)cos(ang), (float)sin(ang));
  }
}

__global__ void k_ws2(float* w_s2, const double* lg, const double* wq){
  int tid = blockIdx.x*256 + threadIdx.x;
  if (tid >= NB_IN*NLM) return;
  int b = tid / NLM, lm = tid % NLM;
  int l = lidx(lm); int m = lm - l*l - l;
  double beta = PI_D*(2*b+1)/256.0;
  w_s2[tid] = (float)(wigner_d(l, m, 0, beta, lg) * wq[b]);
}

// dinv2[b][packed r] = (2l+1) * d^l_{m,n}(beta_b), m>=0 half-plane, packed in l
__global__ void k_dinv2(float* dinv2, const int* ridx, const double* lg){
  int tid = blockIdx.x*256 + threadIdx.x;
  if (tid >= TWOB*NPACK) return;
  int b = tid / NPACK, r = tid % NPACK;
  int info = ridx[r];
  int mj = info & 255, n = ((info>>8)&255) - 19, l = info>>16;
  double beta = PI_D*(2*b+1)/80.0;
  dinv2[tid] = (float)((double)(2*l+1) * wigner_d(l, mj, n, beta, lg));
}

__global__ void k_Fc(float2* Fc, const double* lg){
  int tid = blockIdx.x*256 + threadIdx.x;
  if (tid >= 24*NLM) return;
  int p = tid / NLM, lm = tid % NLM;
  int l = lidx(lm); int m = lm - l*l - l;
  double beta = PI_D*(double)(p/8 + 1)/24.0;
  double alpha = (double)(p%8)*(PI_D/4.0);
  double d = wigner_d(l, m, 0, beta, lg);
  double a = (double)m*alpha;            // conj(F_k) => e^{+i m alpha}
  Fc[tid] = make_float2((float)(d*cos(a)), (float)(d*sin(a)));
}

__global__ void k_yc(const float* ker, const float2* Fc, float2* yc){
  int tid = blockIdx.x*256 + threadIdx.x;
  if (tid >= NLM*NZO) return;
  int lm = tid / 512, io = tid % 512;
  float2 acc = make_float2(0.f, 0.f);
  for (int p = 0; p < 24; ++p){
    float kv = ker[io*24 + p];          // [i][o][p], io = i*32+o
    float2 f = Fc[p*NLM + lm];
    acc.x += kv*f.x; acc.y += kv*f.y;
  }
  acc.x *= (float)SCALING; acc.y *= (float)SCALING;
  yc[(size_t)lm*512 + io] = acc;        // [lm][i*32+o]
}

// ---- main pipeline -----------------------------------------------------
// xf[mj][b][zi] = sum_a x[zi][b][a] * e^{-2pi i (mj-19) a/128}
__global__ __launch_bounds__(256) void k_dft(const float* x, const float2* tw, float2* xf){
  __shared__ float2 twl[NBINS*129];     // padded stride vs 32 banks
  __shared__ float rows[4][128];
  int t = threadIdx.x;
  for (int e = t; e < NBINS*128; e += 256){
    int mj = e >> 7, a = e & 127;
    twl[mj*129 + a] = tw[e];
  }
  int g = t >> 6, lane = t & 63;
  int r = blockIdx.x*4 + g;
  int zi = r & 255, b = r >> 8;
  const float* xr = x + ((size_t)zi*128 + b)*128;
  rows[g][lane]    = xr[lane];
  rows[g][lane+64] = xr[lane+64];
  __syncthreads();
  if (lane < NBINS){
    float2 acc = make_float2(0.f, 0.f);
    const float2* twr = twl + lane*129;
    const float* rw = rows[g];
    for (int a = 0; a < 128; ++a){
      float v = rw[a]; float2 w = twr[a];
      acc.x += v*w.x; acc.y += v*w.y;
    }
    xf[((size_t)lane*128 + b)*256 + zi] = acc;
  }
}

// xl[lm][zi] = sum_b w_s2[b][lm] * xf[bin(lm)][b][zi]
__global__ void k_xl(const float2* xf, const float* w_s2, float2* xl){
  int lm = blockIdx.x; int zi = threadIdx.x;
  int l = lidx(lm); int m = lm - l*l - l;
  int bin = m + 19;
  float2 acc = make_float2(0.f, 0.f);
  for (int b = 0; b < 128; ++b){
    float w = w_s2[b*NLM + lm];
    float2 v = xf[((size_t)bin*128 + b)*256 + zi];
    acc.x += w*v.x; acc.y += w*v.y;
  }
  xl[(size_t)lm*256 + zi] = acc;
}

// zl2[zo][packed r] = sum_i xl[l^2+l+m][z*16+i] * yc[l^2+l+n][i*32+o], m>=0 only
__global__ void k_zl2(const float2* xl, const float2* yc, const int* ridx, float2* zl2){
  int tid = blockIdx.x*256 + threadIdx.x;
  int zo = tid / NPACK, r = tid % NPACK;
  int info = ridx[r];
  int mj = info & 255, n = ((info>>8)&255) - 19, l = info>>16;
  int z = zo >> 5, o = zo & 31;
  const float2* xr = xl + (size_t)(l*l + l + mj)*256 + z*16;
  const float2* yr = yc + (size_t)(l*l + l + n)*512 + o;
  float2 acc = make_float2(0.f, 0.f);
  for (int i = 0; i < 16; ++i){
    float2 a = xr[i], bb = yr[i*32];
    acc.x += a.x*bb.x - a.y*bb.y;
    acc.y += a.x*bb.y + a.y*bb.x;
  }
  zl2[tid] = acc;
}

// per (zo,b): C[m>=0][n] = sum_l dinv2*zl2 ; G = iDFT_n ; out = hermitian iDFT_m + bias
__global__ __launch_bounds__(256) void k_syn2(const float2* zl2, const float* dinv2,
                                              const int* pair_off, const float2* wsyn,
                                              const float* bias, float* out){
  __shared__ float2 Cs[NPAIR];      // [mj][njs] 20x39
  __shared__ float2 Gs[20*40];      // [mj][g]
  __shared__ float2 Wns[39*40];     // [njs][g]
  __shared__ float2 Wms[20*40];     // [mj][a]
  int blk = blockIdx.x;             // zo*40 + b
  int b = blk % 40, zo = blk / 40;
  int o = zo & 31;
  int t = threadIdx.x;
  for (int idx = t; idx < 1560; idx += 256) Wns[idx] = wsyn[idx];
  for (int idx = t; idx < 800;  idx += 256) Wms[idx] = wsyn[1560+idx];
  __syncthreads();

  const float2* zrow = zl2 + (size_t)zo*NPACK;
  const float*  drow = dinv2 + (size_t)b*NPACK;
  for (int p = t; p < NPAIR; p += 256){
    int o0 = pair_off[p], o1 = pair_off[p+1];
    float2 acc = make_float2(0.f, 0.f);
    for (int k = o0; k < o1; ++k){
      float dv = drow[k]; float2 zv = zrow[k];
      acc.x += dv*zv.x; acc.y += dv*zv.y;
    }
    Cs[p] = acc;
  }
  __syncthreads();

  for (int idx = t; idx < 800; idx += 256){
    int mj = idx/40, g = idx%40;
    const float2* crow = Cs + mj*39;
    const float2* wg = Wns + g;
    float2 acc = make_float2(0.f, 0.f);
    for (int nj = 0; nj < 39; ++nj){
      float2 c = crow[nj]; float2 w = wg[nj*40];
      acc.x += c.x*w.x - c.y*w.y;
      acc.y += c.x*w.y + c.y*w.x;
    }
    Gs[idx] = acc;
  }
  __syncthreads();

  float bv = bias[o];
  float* orow = out + (size_t)blk*1600;
  for (int idx = t; idx < 1600; idx += 256){
    int a = idx/40, g = idx%40;
    float acc = 0.f;
    const float2* gcol = Gs + g;
    const float2* wa = Wms + a;
    for (int mj = 1; mj < 20; ++mj){
      float2 gv = gcol[mj*40];
      float2 w  = wa[mj*40];
      acc += gv.x*w.x - gv.y*w.y;
    }
    orow[idx] = Gs[g].x + 2.f*acc + bv;
  }
}

extern "C" void kernel_launch(void* const* d_in, const int* in_sizes, int n_in,
                              void* d_out, int out_size, void* d_ws, size_t ws_size,
                              hipStream_t stream) {
  const float* x    = (const float*)d_in[0];
  const float* ker  = (const float*)d_in[1];
  const float* bias = (const float*)d_in[2];
  float* out = (float*)d_out;

  char* ws = (char*)d_ws;
  size_t cur = 0;
  auto alloc = [&](size_t bytes)->char*{
    char* p = ws + cur;
    cur += (bytes + 255) & ~(size_t)255;
    return p;
  };
  double* lg    = (double*)alloc(64*8);
  double* wq    = (double*)alloc(128*8);
  int*    poff  = (int*)   alloc((NPAIR+1)*4);
  int*    ridx  = (int*)   alloc(NPACK*4);
  float2* tw    = (float2*)alloc((size_t)NBINS*128*8);
  float2* wsyn  = (float2*)alloc((size_t)2360*8);
  float*  w_s2  = (float*) alloc((size_t)NB_IN*NLM*4);
  float*  dinv2 = (float*) alloc((size_t)TWOB*NPACK*4);
  float2* Fc    = (float2*)alloc((size_t)24*NLM*8);
  float2* yc    = (float2*)alloc((size_t)NLM*NZO*8);
  float2* xf    = (float2*)alloc((size_t)NBINS*128*256*8);
  float2* xl    = (float2*)alloc((size_t)NLM*256*8);
  float2* zl2   = (float2*)alloc((size_t)NZO*NPACK*8);
  (void)ws_size; (void)in_sizes; (void)n_in; (void)out_size;

  k_init <<<1, 128, 0, stream>>>(lg, wq, poff, ridx);
  k_tw   <<<(NBINS*128 + 255)/256, 256, 0, stream>>>(tw);
  k_wsyn <<<1, 256, 0, stream>>>(wsyn);
  k_ws2  <<<(NB_IN*NLM)/256, 256, 0, stream>>>(w_s2, lg, wq);
  k_dinv2<<<(TWOB*NPACK + 255)/256, 256, 0, stream>>>(dinv2, ridx, lg);
  k_Fc   <<<(24*NLM + 255)/256, 256, 0, stream>>>(Fc, lg);
  k_yc   <<<(NLM*NZO)/256, 256, 0, stream>>>(ker, Fc, yc);

  k_dft  <<<(256*128)/4, 256, 0, stream>>>(x, tw, xf);
  k_xl   <<<NLM, 256, 0, stream>>>(xf, w_s2, xl);
  k_zl2  <<<(NZO*NPACK)/256, 256, 0, stream>>>(xl, yc, ridx, zl2);
  k_syn2 <<<NZO*TWOB, 256, 0, stream>>>(zl2, dinv2, poff, wsyn, bias, out);
}

// Round 4
// 813.190 us; speedup vs baseline: 1.3812x; 1.2016x over previous
//
#include <hip/hip_runtime.h>
#include <math.h>

#define NB_IN   128
#define NBINS   39
#define NLM     400
#define NZO     512
#define NPAIR   780
#define NPACK   5530
#define TWOB    40
#define PI_D    3.14159265358979323846
#define SCALING 0.008164965809277261

__host__ __device__ __forceinline__ int loffd(int l){ return l*(4*l*l + 3*l - 1)/6; }

__device__ __forceinline__ int lidx(int lm){
  int l = (int)sqrtf((float)lm);
  while ((l+1)*(l+1) <= lm) ++l;
  while (l*l > lm) --l;
  return l;
}

// Wigner little-d via Jacobi sum (one-shot, used by cheap kernels only)
__device__ double wigner_d(int l, int m, int n, double beta, const double* lg){
  double cb = cos(0.5*beta), sb = sin(0.5*beta);
  double lcb = log(cb), lsb = log(sb);
  double pref = 0.5*(lg[l+m]+lg[l-m]+lg[l+n]+lg[l-n]);
  int s0 = 0 > (n-m) ? 0 : (n-m);
  int s1 = (l+n) < (l-m) ? (l+n) : (l-m);
  double val = 0.0;
  for (int s = s0; s <= s1; ++s){
    double c = pref - (lg[l+n-s]+lg[s]+lg[m-n+s]+lg[l-m-s]);
    double t = exp(c + (double)(2*l+n-m-2*s)*lcb + (double)(m-n+2*s)*lsb);
    val += ((m-n+s)&1) ? -t : t;
  }
  return val;
}

// fast Wigner: 2 log + 1 exp + ratio recurrence over s (fp64)
__device__ double wigner_fast(int l, int m, int n, double beta, const double* lg){
  double cb = cos(0.5*beta), sb = sin(0.5*beta);
  double lcb = log(cb), lsb = log(sb);
  double pref = 0.5*(lg[l+m]+lg[l-m]+lg[l+n]+lg[l-n]);
  int s0 = 0 > (n-m) ? 0 : (n-m);
  int s1 = (l+n) < (l-m) ? (l+n) : (l-m);
  double ratio = (sb*sb)/(cb*cb);
  double t = exp(pref - (lg[l+n-s0]+lg[s0]+lg[m-n+s0]+lg[l-m-s0])
               + (double)(2*l+n-m-2*s0)*lcb + (double)(m-n+2*s0)*lsb);
  double sgn = ((m-n+s0)&1) ? -1.0 : 1.0;
  double acc = 0.0;
  for (int s = s0; s <= s1; ++s){
    acc += sgn*t;
    sgn = -sgn;
    t *= ratio * ((double)((l+n-s)*(l-m-s)) / (double)((s+1)*(m-n+s+1)));
  }
  return acc;
}

// ---- constants -------------------------------------------------------
__global__ void k_init(double* lg, double* wq, int* ridx, int* psort, int* npre){
  int t = threadIdx.x;  // 128
  if (t == 0){
    lg[0] = 0.0; double acc = 0.0;
    for (int k = 1; k <= 40; ++k){ acc += log((double)k); lg[k] = acc; }
  }
  if (t == 1){
    int off = 0;
    for (int l = 0; l < 20; ++l)
      for (int mj = 0; mj <= l; ++mj)
        for (int njs = 19-l; njs <= 19+l; ++njs)
          ridx[off++] = mj | (njs<<8) | (l<<16);
  }
  if (t == 2){
    int cnt[20], pos[20];
    for (int i = 0; i < 20; ++i) cnt[i] = 0;
    for (int p = 0; p < NPAIR; ++p){
      int mj = p/39, d = p%39 - 19, ad = d<0?-d:d;
      int lm_ = mj > ad ? mj : ad; cnt[lm_]++;
    }
    int run = 0;
    for (int l = 0; l < 20; ++l){ pos[l] = run; run += cnt[l]; npre[l] = run; }
    for (int p = 0; p < NPAIR; ++p){
      int mj = p/39, njs = p%39, d = njs - 19, ad = d<0?-d:d;
      int lm_ = mj > ad ? mj : ad;
      psort[pos[lm_]++] = mj | (njs<<8);
    }
  }
  double theta = PI_D*(2*t+1)/256.0;
  double s = 0.0;
  for (int k = 0; k < 64; ++k) s += sin((2*k+1)*theta)/(double)(2*k+1);
  wq[t] = (2.0/64.0)*sin(theta)*s;
}

__global__ void k_wsyn(float2* wsyn){
  for (int idx = threadIdx.x; idx < 1560+800; idx += 256){
    double ang;
    if (idx < 1560){
      int njs = idx/40, g = idx%40;
      ang = 2.0*PI_D*(double)(njs-19)*(double)g/40.0;
    } else {
      int r = idx-1560; int mj = r/40, a = r%40;
      ang = 2.0*PI_D*(double)mj*(double)a/40.0;
    }
    wsyn[idx] = make_float2((float)cos(ang), (float)sin(ang));
  }
}

// w_s2: thread = (lm, 16-b chunk)
__global__ void k_ws2(float* w_s2, const double* lg, const double* wq){
  int tid = blockIdx.x*256 + threadIdx.x;
  if (tid >= 400*8) return;
  int lm = tid >> 3, bc = tid & 7;
  int l = lidx(lm); int m = lm - l*l - l;
  for (int j = 0; j < 16; ++j){
    int b = bc*16 + j;
    double beta = PI_D*(2*b+1)/256.0;
    w_s2[b*NLM + lm] = (float)(wigner_fast(l, m, 0, beta, lg) * wq[b]);
  }
}

// dinv2 rows b=0..19, l-major packed
__global__ void k_dinv2(float* dinv2, const int* ridx, const double* lg){
  int k = blockIdx.x*256 + threadIdx.x;
  if (k >= NPACK) return;
  int info = ridx[k];
  int mj = info & 255, n = ((info>>8)&255) - 19, l = info>>16;
  for (int b = 0; b < 20; ++b){
    double beta = PI_D*(2*b+1)/80.0;
    dinv2[b*NPACK + k] = (float)((double)(2*l+1) * wigner_fast(l, mj, n, beta, lg));
  }
}

// mirror rows b=20..39 via d^l_{m,n}(pi-b) = (-1)^{l+m} d^l_{m,-n}(b)
__global__ void k_dmir(float* dinv2, const int* ridx){
  int tid = blockIdx.x*256 + threadIdx.x;
  if (tid >= 20*NPACK) return;
  int bb = tid / NPACK, k = tid % NPACK;
  int info = ridx[k];
  int mj = info & 255, njs = (info>>8)&255, l = info>>16;
  int srck = loffd(l) + mj*(2*l+1) + (l - (njs-19));
  float v = dinv2[(19-bb)*NPACK + srck];
  dinv2[(20+bb)*NPACK + k] = ((l+mj)&1) ? -v : v;
}

__global__ void k_Fc(float2* Fc, const double* lg){
  int tid = blockIdx.x*256 + threadIdx.x;
  if (tid >= 24*NLM) return;
  int p = tid / NLM, lm = tid % NLM;
  int l = lidx(lm); int m = lm - l*l - l;
  double beta = PI_D*(double)(p/8 + 1)/24.0;
  double alpha = (double)(p%8)*(PI_D/4.0);
  double d = wigner_d(l, m, 0, beta, lg);
  double a = (double)m*alpha;            // conj(F_k)
  Fc[tid] = make_float2((float)(d*cos(a)), (float)(d*sin(a)));
}

// ycT[o][i][lm] = conj(y)*SCALING
__global__ void k_yc(const float* ker, const float2* Fc, float2* ycT){
  int tid = blockIdx.x*256 + threadIdx.x;
  if (tid >= NLM*NZO) return;
  int lm = tid / 512, io = tid % 512;
  int i = io >> 5, o = io & 31;
  float2 acc = make_float2(0.f, 0.f);
  for (int p = 0; p < 24; ++p){
    float kv = ker[io*24 + p];
    float2 f = Fc[p*NLM + lm];
    acc.x += kv*f.x; acc.y += kv*f.y;
  }
  acc.x *= (float)SCALING; acc.y *= (float)SCALING;
  ycT[((size_t)(o*16 + i))*NLM + lm] = acc;
}

// ---- pipeline --------------------------------------------------------
// xf[mj][b][zi] via per-lane phase recurrence
__global__ __launch_bounds__(256) void k_dft(const float* x, float2* xf){
  __shared__ float rows[4][128];
  int t = threadIdx.x, g = t >> 6, lane = t & 63;
  int r = blockIdx.x*4 + g;
  int zi = r & 255, b = r >> 8;
  const float* xr = x + ((size_t)zi*128 + b)*128;
  rows[g][lane]    = xr[lane];
  rows[g][lane+64] = xr[lane+64];
  __syncthreads();
  if (lane < NBINS){
    int m = lane - 19;
    float ang = -2.0f*(float)PI_D*(float)m/128.0f;
    float sn, cs; sincosf(ang, &sn, &cs);
    float wr = 1.f, wi = 0.f;
    float2 acc = make_float2(0.f, 0.f);
    const float* rw = rows[g];
    #pragma unroll 8
    for (int a = 0; a < 128; ++a){
      float v = rw[a];
      acc.x += v*wr; acc.y += v*wi;
      float nr = wr*cs - wi*sn;
      wi = wr*sn + wi*cs; wr = nr;
    }
    xf[((size_t)lane*128 + b)*256 + zi] = acc;
  }
}

// partial beta-contraction: xlp[c][lm][zi], c = 32-b chunk
__global__ void k_xlp(const float2* xf, const float* w_s2, float2* xlp){
  int lm = blockIdx.x, c = blockIdx.y, zi = threadIdx.x;
  int l = lidx(lm); int m = lm - l*l - l;
  int bin = m + 19;
  float2 acc = make_float2(0.f, 0.f);
  for (int b = c*32; b < c*32+32; ++b){
    float w = w_s2[b*NLM + lm];
    float2 v = xf[((size_t)bin*128 + b)*256 + zi];
    acc.x += w*v.x; acc.y += w*v.y;
  }
  xlp[((size_t)(c*NLM + lm))*256 + zi] = acc;
}

// sum chunks -> xlT[zi][lm]
__global__ void k_xlsum(const float2* xlp, float2* xlT){
  int lm = blockIdx.x, zi = threadIdx.x;
  float2 s = make_float2(0.f, 0.f);
  for (int c = 0; c < 4; ++c){
    float2 v = xlp[((size_t)(c*NLM + lm))*256 + zi];
    s.x += v.x; s.y += v.y;
  }
  xlT[(size_t)zi*NLM + lm] = s;
}

// zl2[zo][k] (l-major packed), fully coalesced
__global__ void k_zl2(const float2* xlT, const float2* ycT, const int* ridx, float2* zl2){
  int tid = blockIdx.x*256 + threadIdx.x;
  int zo = tid / NPACK, k = tid % NPACK;
  int info = ridx[k];
  int mj = info & 255, njs = (info>>8)&255, l = info>>16;
  int z = zo >> 5, o = zo & 31;
  int lmm = l*l + l + mj;
  int lmn = l*l + l + (njs - 19);
  float2 acc = make_float2(0.f, 0.f);
  for (int i = 0; i < 16; ++i){
    float2 a  = xlT[(size_t)(z*16 + i)*NLM + lmm];
    float2 bb = ycT[(size_t)(o*16 + i)*NLM + lmn];
    acc.x += a.x*bb.x - a.y*bb.y;
    acc.y += a.x*bb.y + a.y*bb.x;
  }
  zl2[tid] = acc;
}

// fused synthesis per (zo,b)
__global__ __launch_bounds__(256) void k_syn3(const float2* zl2, const float* dinv2,
                                              const int* psort, const int* npre,
                                              const float2* wsyn, const float* bias,
                                              float* out){
  __shared__ float2 zS[1602];
  __shared__ float  dS[1602];
  __shared__ float2 Cs[NPAIR];
  __shared__ __align__(16) float2 Gs[800];
  __shared__ __align__(16) float2 Wns[1560];
  __shared__ __align__(16) float2 Wms[800];

  int bid = blockIdx.x;
  int blk = (bid & 7)*2560 + (bid >> 3);   // XCD-contiguous zo runs
  int b = blk % 40, zo = blk / 40;
  int o = zo & 31;
  int t = threadIdx.x;

  for (int idx = t; idx < 1560; idx += 256) Wns[idx] = wsyn[idx];
  for (int idx = t; idx < 800;  idx += 256) Wms[idx] = wsyn[1560+idx];

  // ---- stage 1: C[m>=0][n] = sum_l dinv*zl, layer-staged ----
  const float2* zrow = zl2 + (size_t)zo*NPACK;
  const float*  drow = dinv2 + (size_t)b*NPACK;
  int pk0 = psort[t], pk1 = psort[t+256];
  int pk2 = psort[(t+512<NPAIR)?(t+512):0];
  int pk3 = psort[(t+768<NPAIR)?(t+768):0];
  int mj0 = pk0&255, nj0 = (pk0>>8)&255;
  int mj1 = pk1&255, nj1 = (pk1>>8)&255;
  int mj2 = pk2&255, nj2 = (pk2>>8)&255;
  int mj3 = pk3&255, nj3 = (pk3>>8)&255;
  float2 c0 = make_float2(0.f,0.f), c1 = c0, c2 = c0, c3 = c0;

  const int gl[5] = {0, 13, 16, 18, 20};
  for (int grp = 0; grp < 4; ++grp){
    int base = loffd(gl[grp]);
    int size = loffd(gl[grp+1]) - base;
    __syncthreads();
    for (int i = t; i < size; i += 256){ zS[i] = zrow[base+i]; dS[i] = drow[base+i]; }
    __syncthreads();
    for (int l = gl[grp]; l < gl[grp+1]; ++l){
      int W = 2*l+1;
      int off = loffd(l) - base - 19 + l;
      int np = npre[l];
      if (t < np){
        int id = off + mj0*W + nj0;
        float dv = dS[id]; float2 zv = zS[id];
        c0.x += dv*zv.x; c0.y += dv*zv.y;
      }
      if (t+256 < np){
        int id = off + mj1*W + nj1;
        float dv = dS[id]; float2 zv = zS[id];
        c1.x += dv*zv.x; c1.y += dv*zv.y;
      }
      if (t+512 < np){
        int id = off + mj2*W + nj2;
        float dv = dS[id]; float2 zv = zS[id];
        c2.x += dv*zv.x; c2.y += dv*zv.y;
      }
      if (t+768 < np){
        int id = off + mj3*W + nj3;
        float dv = dS[id]; float2 zv = zS[id];
        c3.x += dv*zv.x; c3.y += dv*zv.y;
      }
    }
  }
  __syncthreads();
  Cs[mj0*39 + nj0] = c0;
  Cs[mj1*39 + nj1] = c1;
  if (t+512 < NPAIR) Cs[mj2*39 + nj2] = c2;
  if (t+768 < NPAIR) Cs[mj3*39 + nj3] = c3;
  __syncthreads();

  // ---- stage 2: G[mj][g] = sum_n C[mj][n] Wn[n][g], 2x2 tiles ----
  if (t < 200){
    int mj = 2*(t/20), g = 2*(t%20);
    float2 a00 = make_float2(0.f,0.f), a01 = a00, a10 = a00, a11 = a00;
    for (int nj = 0; nj < 39; ++nj){
      float2 cA = Cs[mj*39+nj], cB = Cs[(mj+1)*39+nj];
      float4 w = *(const float4*)&Wns[nj*40 + g];
      a00.x += cA.x*w.x - cA.y*w.y; a00.y += cA.x*w.y + cA.y*w.x;
      a01.x += cA.x*w.z - cA.y*w.w; a01.y += cA.x*w.w + cA.y*w.z;
      a10.x += cB.x*w.x - cB.y*w.y; a10.y += cB.x*w.y + cB.y*w.x;
      a11.x += cB.x*w.z - cB.y*w.w; a11.y += cB.x*w.w + cB.y*w.z;
    }
    *(float4*)&Gs[mj*40+g]     = make_float4(a00.x,a00.y,a01.x,a01.y);
    *(float4*)&Gs[(mj+1)*40+g] = make_float4(a10.x,a10.y,a11.x,a11.y);
  }
  __syncthreads();

  // ---- stage 3: out[a][g] = G0[g] + 2*sum_{mj>=1} Re(G*Wm) + bias ----
  if (t < 200){
    int a = 2*(t/10), g4 = 4*(t%10);
    float ac0[4] = {0.f,0.f,0.f,0.f};
    float ac1[4] = {0.f,0.f,0.f,0.f};
    for (int mj = 1; mj < 20; ++mj){
      float4 wm = *(const float4*)&Wms[mj*40 + a];
      float4 gA = *(const float4*)&Gs[mj*40 + g4];
      float4 gB = *(const float4*)&Gs[mj*40 + g4 + 2];
      ac0[0] += gA.x*wm.x - gA.y*wm.y;
      ac0[1] += gA.z*wm.x - gA.w*wm.y;
      ac0[2] += gB.x*wm.x - gB.y*wm.y;
      ac0[3] += gB.z*wm.x - gB.w*wm.y;
      ac1[0] += gA.x*wm.z - gA.y*wm.w;
      ac1[1] += gA.z*wm.z - gA.w*wm.w;
      ac1[2] += gB.x*wm.z - gB.y*wm.w;
      ac1[3] += gB.z*wm.z - gB.w*wm.w;
    }
    float4 G0a = *(const float4*)&Gs[g4];
    float4 G0b = *(const float4*)&Gs[g4+2];
    float bv = bias[o];
    float* orow = out + (size_t)blk*1600;
    float4 o0 = make_float4(G0a.x + 2.f*ac0[0] + bv, G0a.z + 2.f*ac0[1] + bv,
                            G0b.x + 2.f*ac0[2] + bv, G0b.z + 2.f*ac0[3] + bv);
    float4 o1 = make_float4(G0a.x + 2.f*ac1[0] + bv, G0a.z + 2.f*ac1[1] + bv,
                            G0b.x + 2.f*ac1[2] + bv, G0b.z + 2.f*ac1[3] + bv);
    *(float4*)(orow + a*40 + g4)     = o0;
    *(float4*)(orow + (a+1)*40 + g4) = o1;
  }
}

extern "C" void kernel_launch(void* const* d_in, const int* in_sizes, int n_in,
                              void* d_out, int out_size, void* d_ws, size_t ws_size,
                              hipStream_t stream) {
  const float* x    = (const float*)d_in[0];
  const float* ker  = (const float*)d_in[1];
  const float* bias = (const float*)d_in[2];
  float* out = (float*)d_out;

  char* ws = (char*)d_ws;
  size_t cur = 0;
  auto alloc = [&](size_t bytes)->char*{
    char* p = ws + cur;
    cur += (bytes + 255) & ~(size_t)255;
    return p;
  };
  double* lg    = (double*)alloc(64*8);
  double* wq    = (double*)alloc(128*8);
  int*    ridx  = (int*)   alloc(NPACK*4);
  int*    psort = (int*)   alloc(NPAIR*4);
  int*    npre  = (int*)   alloc(32*4);
  float2* wsyn  = (float2*)alloc((size_t)2360*8);
  float*  w_s2  = (float*) alloc((size_t)NB_IN*NLM*4);
  float*  dinv2 = (float*) alloc((size_t)TWOB*NPACK*4);
  float2* Fc    = (float2*)alloc((size_t)24*NLM*8);
  float2* ycT   = (float2*)alloc((size_t)512*400*8);
  float2* xf    = (float2*)alloc((size_t)NBINS*128*256*8);
  float2* xlp   = (float2*)alloc((size_t)4*NLM*256*8);
  float2* xlT   = (float2*)alloc((size_t)256*NLM*8);
  float2* zl2   = (float2*)alloc((size_t)NZO*NPACK*8);
  (void)ws_size; (void)in_sizes; (void)n_in; (void)out_size;

  k_init <<<1, 128, 0, stream>>>(lg, wq, ridx, psort, npre);
  k_wsyn <<<1, 256, 0, stream>>>(wsyn);
  k_ws2  <<<13, 256, 0, stream>>>(w_s2, lg, wq);
  k_dinv2<<<22, 256, 0, stream>>>(dinv2, ridx, lg);
  k_dmir <<<(20*NPACK + 255)/256, 256, 0, stream>>>(dinv2, ridx);
  k_Fc   <<<38, 256, 0, stream>>>(Fc, lg);
  k_yc   <<<800, 256, 0, stream>>>(ker, Fc, ycT);

  k_dft  <<<(256*128)/4, 256, 0, stream>>>(x, xf);
  k_xlp  <<<dim3(NLM, 4), 256, 0, stream>>>(xf, w_s2, xlp);
  k_xlsum<<<NLM, 256, 0, stream>>>(xlp, xlT);
  k_zl2  <<<(NZO*NPACK)/256, 256, 0, stream>>>(xlT, ycT, ridx, zl2);
  k_syn3 <<<NZO*TWOB, 256, 0, stream>>>(zl2, dinv2, psort, npre, wsyn, bias, out);
}